// Round 1
// baseline (436.552 us; speedup 1.0000x reference)
//
#include <hip/hip_runtime.h>
#include <math.h>

#define B_ 4
#define C_ 64
#define M_ 8
#define H_ 224
#define W_ 224
#define N_ (H_*W_)        // 50176
#define CN_ (C_*N_)       // 3211264
#define MN_ (M_*N_)       // 401408
#define BCN_ (B_*CN_)
#define BMN_ (B_*MN_)

__device__ __forceinline__ float relu6f(float v){ return fminf(fmaxf(v,0.0f),6.0f); }
__device__ __forceinline__ float softplusf(float v){
  return v > 0.0f ? v + log1pf(expf(-v)) : log1pf(expf(v));
}

// ---------------------------------------------------------------------------
// K1: h = relu6(bn(conv1x1(x, fc1_w)))    lane = out-channel, wave = 32 pixels
// ---------------------------------------------------------------------------
__global__ __launch_bounds__(256) void k_fc1(const float* __restrict__ x,
                                             const float* __restrict__ w,
                                             const float* __restrict__ bn,
                                             float* __restrict__ h)
{
  __shared__ float wt[64*65];              // wt[c][o], stride 65 -> conflict-free
  const int tid = threadIdx.x;
  for (int idx = tid; idx < 4096; idx += 256) {
    const int o = idx >> 6, c = idx & 63;
    wt[c*65 + o] = w[idx];                 // w[o][c]
  }
  __syncthreads();
  const int lane = tid & 63;
  const int wave = tid >> 6;
  const float inv  = bn[lane] / sqrtf(bn[192 + lane] + 1e-5f);
  const float beta = bn[64 + lane] - bn[128 + lane] * inv;

  const int b  = blockIdx.x / 392;
  const int pg = blockIdx.x % 392;
  int pix0 = pg * 128 + wave * 32;
  pix0 = __builtin_amdgcn_readfirstlane(pix0);
  const float* xb = x + (size_t)b * CN_ + pix0;

  float acc[32];
  #pragma unroll
  for (int p = 0; p < 32; ++p) acc[p] = 0.0f;

  #pragma unroll 4
  for (int c = 0; c < 64; ++c) {
    const float wv = wt[c*65 + lane];
    const float4* xp = (const float4*)(xb + c * N_);
    #pragma unroll
    for (int p4 = 0; p4 < 8; ++p4) {
      const float4 xv = xp[p4];            // wave-uniform broadcast load
      acc[p4*4+0] = fmaf(wv, xv.x, acc[p4*4+0]);
      acc[p4*4+1] = fmaf(wv, xv.y, acc[p4*4+1]);
      acc[p4*4+2] = fmaf(wv, xv.z, acc[p4*4+2]);
      acc[p4*4+3] = fmaf(wv, xv.w, acc[p4*4+3]);
    }
  }
  float* hb = h + (size_t)b * CN_ + (size_t)lane * N_ + pix0;
  #pragma unroll
  for (int p4 = 0; p4 < 8; ++p4) {
    float4 o4;
    o4.x = relu6f(fmaf(acc[p4*4+0], inv, beta));
    o4.y = relu6f(fmaf(acc[p4*4+1], inv, beta));
    o4.z = relu6f(fmaf(acc[p4*4+2], inv, beta));
    o4.w = relu6f(fmaf(acc[p4*4+3], inv, beta));
    ((float4*)hb)[p4] = o4;
  }
}

// ---------------------------------------------------------------------------
// K2: s = relu6(bn1(dw5x5(h))) + relu6(bn2(dw3x3(h)))   32x32 tile per (b,c)
// ---------------------------------------------------------------------------
__global__ __launch_bounds__(256) void k_dw(const float* __restrict__ h,
                                            const float* __restrict__ w5,
                                            const float* __restrict__ w3,
                                            const float* __restrict__ bn1,
                                            const float* __restrict__ bn2,
                                            float* __restrict__ s)
{
  __shared__ float tile[36*37];            // 36 rows, stride 37 (bank spread)
  const int tid = threadIdx.x;
  const int blk = blockIdx.x;              // B*C*49
  const int t   = blk % 49;
  const int bc  = blk / 49;
  const int c   = bc & 63;
  const int tx0 = (t % 7) * 32;
  const int ty0 = (t / 7) * 32;
  const float* hb = h + (size_t)bc * N_;

  for (int idx = tid; idx < 1296; idx += 256) {
    const int ly = idx / 36, lx = idx - ly*36;
    const int gy = ty0 + ly - 2, gx = tx0 + lx - 2;
    float v = 0.0f;
    if (gy >= 0 && gy < H_ && gx >= 0 && gx < W_) v = hb[gy*W_ + gx];
    tile[ly*37 + lx] = v;
  }
  __syncthreads();

  float w5r[25], w3r[9];
  #pragma unroll
  for (int i = 0; i < 25; ++i) w5r[i] = w5[c*25 + i];
  #pragma unroll
  for (int i = 0; i < 9; ++i)  w3r[i] = w3[c*9 + i];
  const float inv1 = bn1[c] / sqrtf(bn1[192+c] + 1e-5f);
  const float bet1 = bn1[64+c] - bn1[128+c]*inv1;
  const float inv2 = bn2[c] / sqrtf(bn2[192+c] + 1e-5f);
  const float bet2 = bn2[64+c] - bn2[128+c]*inv2;

  const int ty  = tid >> 3;
  const int tx4 = (tid & 7) << 2;          // 4 horizontal pixels per thread
  float a5[4] = {0,0,0,0}, a3[4] = {0,0,0,0};
  #pragma unroll
  for (int dy = 0; dy < 5; ++dy) {
    float r[8];
    #pragma unroll
    for (int i = 0; i < 8; ++i) r[i] = tile[(ty+dy)*37 + tx4 + i];
    #pragma unroll
    for (int dx = 0; dx < 5; ++dx) {
      const float wv = w5r[dy*5+dx];
      #pragma unroll
      for (int p = 0; p < 4; ++p) a5[p] = fmaf(wv, r[p+dx], a5[p]);
    }
    if (dy >= 1 && dy <= 3) {
      #pragma unroll
      for (int dx = 1; dx <= 3; ++dx) {
        const float wv = w3r[(dy-1)*3+(dx-1)];
        #pragma unroll
        for (int p = 0; p < 4; ++p) a3[p] = fmaf(wv, r[p+dx], a3[p]);
      }
    }
  }
  float* sb = s + (size_t)bc * N_ + (ty0+ty)*W_ + tx0 + tx4;
  float4 o4;
  o4.x = relu6f(fmaf(a5[0],inv1,bet1)) + relu6f(fmaf(a3[0],inv2,bet2));
  o4.y = relu6f(fmaf(a5[1],inv1,bet1)) + relu6f(fmaf(a3[1],inv2,bet2));
  o4.z = relu6f(fmaf(a5[2],inv1,bet1)) + relu6f(fmaf(a3[2],inv2,bet2));
  o4.w = relu6f(fmaf(a5[3],inv1,bet1)) + relu6f(fmaf(a3[3],inv2,bet2));
  *(float4*)sb = o4;
}

// ---------------------------------------------------------------------------
// K3: V = conv1x1(x,v_w)+v_b + relu6(bn(conv1x1(s,fc2_w)));  K = softplus(k conv)
// ---------------------------------------------------------------------------
__global__ __launch_bounds__(256) void k_vk(const float* __restrict__ x,
                                            const float* __restrict__ s,
                                            const float* __restrict__ vw,
                                            const float* __restrict__ vb,
                                            const float* __restrict__ fw,
                                            const float* __restrict__ fbn,
                                            const float* __restrict__ kw,
                                            const float* __restrict__ kb,
                                            float* __restrict__ V,
                                            float* __restrict__ Kq)
{
  __shared__ float wtv[64*65];
  __shared__ float wtf[64*65];
  __shared__ float wtk[64*9];
  const int tid = threadIdx.x;
  for (int idx = tid; idx < 4096; idx += 256) {
    const int o = idx >> 6, c = idx & 63;
    wtv[c*65+o] = vw[idx];
    wtf[c*65+o] = fw[idx];
  }
  for (int idx = tid; idx < 512; idx += 256) {
    const int m = idx >> 6, c = idx & 63;
    wtk[c*9+m] = kw[idx];                  // kw[m][c]
  }
  __syncthreads();
  const int lane = tid & 63, wave = tid >> 6;
  const float invf = fbn[lane] / sqrtf(fbn[192+lane]+1e-5f);
  const float betf = fbn[64+lane] - fbn[128+lane]*invf;
  const float vbl  = vb[lane];

  const int b  = blockIdx.x / 784;
  const int pg = blockIdx.x % 784;
  int pix0 = pg*64 + wave*16;
  pix0 = __builtin_amdgcn_readfirstlane(pix0);
  const float* xb = x + (size_t)b*CN_ + pix0;
  const float* sb = s + (size_t)b*CN_ + pix0;

  float av[16], af[16];
  #pragma unroll
  for (int p = 0; p < 16; ++p) { av[p]=0.0f; af[p]=0.0f; }

  #pragma unroll 4
  for (int c = 0; c < 64; ++c) {
    const float wv_ = wtv[c*65+lane];
    const float wf_ = wtf[c*65+lane];
    const float4* xp = (const float4*)(xb + c*N_);
    const float4* sp = (const float4*)(sb + c*N_);
    #pragma unroll
    for (int p4 = 0; p4 < 4; ++p4) {
      const float4 xv = xp[p4];
      const float4 sv = sp[p4];
      av[p4*4+0] = fmaf(wv_, xv.x, av[p4*4+0]);
      av[p4*4+1] = fmaf(wv_, xv.y, av[p4*4+1]);
      av[p4*4+2] = fmaf(wv_, xv.z, av[p4*4+2]);
      av[p4*4+3] = fmaf(wv_, xv.w, av[p4*4+3]);
      af[p4*4+0] = fmaf(wf_, sv.x, af[p4*4+0]);
      af[p4*4+1] = fmaf(wf_, sv.y, af[p4*4+1]);
      af[p4*4+2] = fmaf(wf_, sv.z, af[p4*4+2]);
      af[p4*4+3] = fmaf(wf_, sv.w, af[p4*4+3]);
    }
  }
  float* Vb = V + (size_t)b*CN_ + (size_t)lane*N_ + pix0;
  #pragma unroll
  for (int p4 = 0; p4 < 4; ++p4) {
    float4 o4;
    o4.x = av[p4*4+0] + vbl + relu6f(fmaf(af[p4*4+0],invf,betf));
    o4.y = av[p4*4+1] + vbl + relu6f(fmaf(af[p4*4+1],invf,betf));
    o4.z = av[p4*4+2] + vbl + relu6f(fmaf(af[p4*4+2],invf,betf));
    o4.w = av[p4*4+3] + vbl + relu6f(fmaf(af[p4*4+3],invf,betf));
    ((float4*)Vb)[p4] = o4;
  }
  // phase 2: K feature map. lane = (m, j): m in 0..7 rows, j = 2-pixel group
  const int m = lane >> 3, j = lane & 7;
  const float kbm = kb[m];
  float ak0 = 0.0f, ak1 = 0.0f;
  const float* xj = xb + j*2;
  #pragma unroll 4
  for (int c = 0; c < 64; ++c) {
    const float wk_ = wtk[c*9+m];
    const float2 xv = *(const float2*)(xj + c*N_);
    ak0 = fmaf(wk_, xv.x, ak0);
    ak1 = fmaf(wk_, xv.y, ak1);
  }
  float2 ko;
  ko.x = softplusf(ak0 + kbm);
  ko.y = softplusf(ak1 + kbm);
  *(float2*)(Kq + (size_t)b*MN_ + (size_t)m*N_ + pix0 + j*2) = ko;
}

// ---------------------------------------------------------------------------
// K4: KV[b,m,c] = sum_n K[b,m,n]*V[b,c,n];  Ksum[b,m] = sum_n K[b,m,n]
// grid 512 = b(4) x cgroup(8) x chunk(16); butterfly-reduce + atomicAdd
// ---------------------------------------------------------------------------
__global__ __launch_bounds__(256) void k_kv(const float* __restrict__ V,
                                            const float* __restrict__ Kq,
                                            float* __restrict__ KV,
                                            float* __restrict__ Ksum)
{
  const int blk = blockIdx.x;
  const int b   = blk >> 7;
  const int rem = blk & 127;
  const int cg  = rem >> 4;
  const int ch  = rem & 15;
  const int tid = threadIdx.x;
  const int base = ch * 3136;
  const int end  = base + 3136;
  const float* Kb = Kq + (size_t)b*MN_;
  const float* Vb = V  + (size_t)b*CN_ + (size_t)(cg*8)*N_;

  float acc[64];
  #pragma unroll
  for (int i = 0; i < 64; ++i) acc[i] = 0.0f;
  float ks[8] = {0,0,0,0,0,0,0,0};

  for (int n = base + tid; n < end; n += 256) {
    float kv[8];
    #pragma unroll
    for (int m2 = 0; m2 < 8; ++m2) kv[m2] = Kb[m2*N_ + n];
    #pragma unroll
    for (int m2 = 0; m2 < 8; ++m2) ks[m2] += kv[m2];
    #pragma unroll
    for (int c8 = 0; c8 < 8; ++c8) {
      const float vv = Vb[c8*N_ + n];
      #pragma unroll
      for (int m2 = 0; m2 < 8; ++m2)
        acc[m2*8+c8] = fmaf(kv[m2], vv, acc[m2*8+c8]);
    }
  }
  const int lane = tid & 63;
  float mine = 0.0f;
  #pragma unroll
  for (int jj = 0; jj < 64; ++jj) {
    float v = acc[jj];
    v += __shfl_xor(v, 1);
    v += __shfl_xor(v, 2);
    v += __shfl_xor(v, 4);
    v += __shfl_xor(v, 8);
    v += __shfl_xor(v, 16);
    v += __shfl_xor(v, 32);
    if (lane == jj) mine = v;
  }
  atomicAdd(&KV[b*512 + (lane>>3)*64 + cg*8 + (lane&7)], mine);
  if (cg == 0) {
    float mk = 0.0f;
    #pragma unroll
    for (int jj = 0; jj < 8; ++jj) {
      float v = ks[jj];
      v += __shfl_xor(v, 1);
      v += __shfl_xor(v, 2);
      v += __shfl_xor(v, 4);
      v += __shfl_xor(v, 8);
      v += __shfl_xor(v, 16);
      v += __shfl_xor(v, 32);
      if (lane == jj) mk = v;
    }
    if (lane < 8) atomicAdd(&Ksum[b*8 + lane], mk);
  }
}

// ---------------------------------------------------------------------------
// K5: Q on the fly; out = x + gamma * (Q^T KV) / (Q^T (Ksum+eps))
// thread = pixel; x row cached in 64 regs (also the residual)
// ---------------------------------------------------------------------------
__global__ __launch_bounds__(256) void k_out(const float* __restrict__ x,
                                             const float* __restrict__ qw,
                                             const float* __restrict__ qb,
                                             const float* __restrict__ gamma,
                                             const float* __restrict__ KV,
                                             const float* __restrict__ Ksum,
                                             float* __restrict__ out)
{
  __shared__ __align__(16) float kvt[64*12];   // kvt[c][m], stride 12 (16B ok)
  __shared__ __align__(16) float wqt[64*8];    // wqt[c][m]
  __shared__ float ksl[8];
  const int tid = threadIdx.x;
  const int b  = blockIdx.x / 196;
  const int pg = blockIdx.x % 196;
  for (int idx = tid; idx < 512; idx += 256) {
    const int m = idx >> 6, c = idx & 63;
    kvt[c*12 + m] = KV[b*512 + idx];
    wqt[c*8  + m] = qw[idx];                   // qw[m][c]
  }
  if (tid < 8) ksl[tid] = Ksum[b*8 + tid] + 1e-6f;
  __syncthreads();

  const int n = pg*256 + tid;
  const float* xb = x + (size_t)b*CN_ + n;
  float xr[64];
  #pragma unroll
  for (int c = 0; c < 64; ++c) xr[c] = xb[(size_t)c*N_];

  float q[8] = {0,0,0,0,0,0,0,0};
  #pragma unroll
  for (int c = 0; c < 64; ++c) {
    const float4 w0 = *(const float4*)&wqt[c*8];
    const float4 w1 = *(const float4*)&wqt[c*8+4];
    q[0] = fmaf(w0.x, xr[c], q[0]);
    q[1] = fmaf(w0.y, xr[c], q[1]);
    q[2] = fmaf(w0.z, xr[c], q[2]);
    q[3] = fmaf(w0.w, xr[c], q[3]);
    q[4] = fmaf(w1.x, xr[c], q[4]);
    q[5] = fmaf(w1.y, xr[c], q[5]);
    q[6] = fmaf(w1.z, xr[c], q[6]);
    q[7] = fmaf(w1.w, xr[c], q[7]);
  }
  float den = 0.0f;
  #pragma unroll
  for (int m = 0; m < 8; ++m) {
    q[m] = softplusf(q[m] + qb[m]);
    den  = fmaf(q[m], ksl[m], den);
  }
  const float sc = gamma[0] / den;
  float* ob = out + (size_t)b*CN_ + n;
  #pragma unroll
  for (int c = 0; c < 64; ++c) {
    const float4 k0 = *(const float4*)&kvt[c*12];
    const float4 k1 = *(const float4*)&kvt[c*12+4];
    float wv;
    wv = q[0]*k0.x;
    wv = fmaf(q[1], k0.y, wv);
    wv = fmaf(q[2], k0.z, wv);
    wv = fmaf(q[3], k0.w, wv);
    wv = fmaf(q[4], k1.x, wv);
    wv = fmaf(q[5], k1.y, wv);
    wv = fmaf(q[6], k1.z, wv);
    wv = fmaf(q[7], k1.w, wv);
    ob[(size_t)c*N_] = fmaf(sc, wv, xr[c]);
  }
}

// ---------------------------------------------------------------------------
extern "C" void kernel_launch(void* const* d_in, const int* in_sizes, int n_in,
                              void* d_out, int out_size, void* d_ws, size_t ws_size,
                              hipStream_t stream) {
  const float* x      = (const float*)d_in[0];
  const float* gamma  = (const float*)d_in[1];
  const float* q_w    = (const float*)d_in[2];
  const float* q_b    = (const float*)d_in[3];
  const float* k_w    = (const float*)d_in[4];
  const float* k_b    = (const float*)d_in[5];
  const float* v_w    = (const float*)d_in[6];
  const float* v_b    = (const float*)d_in[7];
  const float* fc1_w  = (const float*)d_in[8];
  const float* fc1_bn = (const float*)d_in[9];
  const float* c1_w   = (const float*)d_in[10];
  const float* c1_bn  = (const float*)d_in[11];
  const float* c2_w   = (const float*)d_in[12];
  const float* c2_bn  = (const float*)d_in[13];
  const float* fc2_w  = (const float*)d_in[14];
  const float* fc2_bn = (const float*)d_in[15];
  float* outp = (float*)d_out;

  float* ws   = (float*)d_ws;
  float* bufA = ws;                        // h, later reused for V
  float* bufS = ws + (size_t)BCN_;
  float* bufK = ws + (size_t)2*BCN_;
  float* kv   = ws + (size_t)2*BCN_ + BMN_;
  float* ksum = kv + 2048;

  hipMemsetAsync(kv, 0, (2048 + 32)*sizeof(float), stream);

  k_fc1<<<dim3(B_*392), dim3(256), 0, stream>>>(x, fc1_w, fc1_bn, bufA);
  k_dw <<<dim3(B_*C_*49), dim3(256), 0, stream>>>(bufA, c1_w, c2_w, c1_bn, c2_bn, bufS);
  k_vk <<<dim3(B_*784), dim3(256), 0, stream>>>(x, bufS, v_w, v_b, fc2_w, fc2_bn,
                                                k_w, k_b, bufA /*V overwrites h*/, bufK);
  k_kv <<<dim3(512), dim3(256), 0, stream>>>(bufA, bufK, kv, ksum);
  k_out<<<dim3(B_*196), dim3(256), 0, stream>>>(x, q_w, q_b, gamma, kv, ksum, outp);
}